// Round 10
// baseline (126.418 us; speedup 1.0000x reference)
//
#include <hip/hip_runtime.h>
#include <hip/hip_bf16.h>

#define BB 4
#define NN 10000
#define EE 320000
#define HH 8
#define NSLICE 32             // edge slices per (batch, head-pair) -> grid 512 = 2 blocks/CU
#define ESL (EE / NSLICE)     // 10000 edges per slice
#define UU 4                  // edges batched per thread (MLP)
#define SCALE 16777216.0f     // 2^24 fixed-point
#define INVSC (1.0f / 16777216.0f)

typedef float f4 __attribute__((ext_vector_type(4)));
typedef short s8v __attribute__((ext_vector_type(8)));
typedef unsigned short u16x8 __attribute__((ext_vector_type(8)));

__device__ __forceinline__ unsigned short f2bf(float f) {
  unsigned int u = __float_as_uint(f);
  u += 0x7FFFu + ((u >> 16) & 1u);
  return (unsigned short)(u >> 16);
}
__device__ __forceinline__ float bf2f(unsigned short s) {
  return __uint_as_float(((unsigned int)s) << 16);
}
__device__ __forceinline__ unsigned int ordf(float f) {
  unsigned int u = __float_as_uint(f);
  return (u & 0x80000000u) ? ~u : (u | 0x80000000u);
}
__device__ __forceinline__ float unordf(unsigned int u) {
  unsigned int b = (u & 0x80000000u) ? (u & 0x7FFFFFFFu) : ~u;
  return __uint_as_float(b);
}

// ---------------- W transpose + bf16 convert: Wt[n][k] = bf16(W[k][n]) ----------------
__global__ __launch_bounds__(256) void k_transpose(const float* __restrict__ W,
                                                   unsigned short* __restrict__ Wt) {
  __shared__ float tile[64][65];
  const int n0 = blockIdx.x * 64, k0 = blockIdx.y * 64;
  for (int i = threadIdx.x; i < 4096; i += 256) {
    int kk = i >> 6, nn = i & 63;
    tile[kk][nn] = W[(size_t)(k0 + kk) * 256 + n0 + nn];
  }
  __syncthreads();
  for (int i = threadIdx.x; i < 4096; i += 256) {
    int nn = i >> 6, kk = i & 63;
    Wt[(size_t)(n0 + nn) * 256 + (k0 + kk)] = f2bf(tile[kk][nn]);
  }
}

// ---- GEMM + fused score epilogue: wx = x@W (bf16 MFMA), s_src/s_dst per row/head ----
__global__ __launch_bounds__(256, 2) void k_gemm(const float* __restrict__ x,
                                                 const unsigned short* __restrict__ Wt,
                                                 const float* __restrict__ a,
                                                 float* __restrict__ wx,
                                                 float* __restrict__ s_src,
                                                 float* __restrict__ s_dst) {
  __shared__ unsigned short sA[64][40];   // [row][k], padded
  __shared__ unsigned short sB[256][40];  // [col][k] (= W^T), padded
  const int tid = threadIdx.x;
  const int lane = tid & 63;
  const int wv = tid >> 6;
  const int row0 = blockIdx.x << 6;
  const int fr = lane & 15;
  const int fg = lane >> 4;
  f4 acc[4][4] = {};
  const int ar = tid >> 2;
  const int ak = (tid & 3) << 3;

  for (int k0 = 0; k0 < 256; k0 += 32) {
    const float* xp = x + (size_t)(row0 + ar) * 256 + k0 + ak;
    f4 v0 = *(const f4*)xp;
    f4 v1 = *(const f4*)(xp + 4);
    u16x8 av;
    av[0] = f2bf(v0[0]); av[1] = f2bf(v0[1]); av[2] = f2bf(v0[2]); av[3] = f2bf(v0[3]);
    av[4] = f2bf(v1[0]); av[5] = f2bf(v1[1]); av[6] = f2bf(v1[2]); av[7] = f2bf(v1[3]);
    *(u16x8*)&sA[ar][ak] = av;
#pragma unroll
    for (int j = 0; j < 4; ++j) {
      int ci = tid + (j << 8);
      int col = ci >> 2;
      int ks = (ci & 3) << 3;
      *(u16x8*)&sB[col][ks] = *(const u16x8*)(Wt + (size_t)col * 256 + k0 + ks);
    }
    __syncthreads();
    s8v afr[4], bfr[4];
#pragma unroll
    for (int m = 0; m < 4; ++m) afr[m] = *(const s8v*)&sA[m * 16 + fr][fg << 3];
#pragma unroll
    for (int n = 0; n < 4; ++n) bfr[n] = *(const s8v*)&sB[wv * 64 + n * 16 + fr][fg << 3];
#pragma unroll
    for (int m = 0; m < 4; ++m)
#pragma unroll
      for (int n = 0; n < 4; ++n)
        acc[m][n] = __builtin_amdgcn_mfma_f32_16x16x32_bf16(afr[m], bfr[n], acc[m][n], 0, 0, 0);
    __syncthreads();
  }
  // C store: D[row][col], col = lane&15, row = (lane>>4)*4 + q
#pragma unroll
  for (int m = 0; m < 4; ++m)
#pragma unroll
    for (int n = 0; n < 4; ++n) {
      int col = wv * 64 + n * 16 + fr;
#pragma unroll
      for (int q = 0; q < 4; ++q) {
        int row = row0 + m * 16 + fg * 4 + q;
        wx[(size_t)row * 256 + col] = acc[m][n][q];
      }
    }
  // fused scores: wave wv owns heads {2wv, 2wv+1}
  const float as0 = a[fr], as1 = a[16 + fr];
  const float ad0 = a[32 + fr], ad1 = a[48 + fr];
#pragma unroll
  for (int m = 0; m < 4; ++m)
#pragma unroll
    for (int q = 0; q < 4; ++q) {
      float p0 = acc[m][0][q] * as0 + acc[m][1][q] * as1;
      float p1 = acc[m][2][q] * as0 + acc[m][3][q] * as1;
      float d0 = acc[m][0][q] * ad0 + acc[m][1][q] * ad1;
      float d1 = acc[m][2][q] * ad0 + acc[m][3][q] * ad1;
#pragma unroll
      for (int msk = 1; msk <= 8; msk <<= 1) {
        p0 += __shfl_xor(p0, msk);
        p1 += __shfl_xor(p1, msk);
        d0 += __shfl_xor(d0, msk);
        d1 += __shfl_xor(d1, msk);
      }
      if (fr == 0) {
        int row = row0 + m * 16 + fg * 4 + q;
        s_src[(size_t)row * 8 + wv * 2]     = p0;
        s_src[(size_t)row * 8 + wv * 2 + 1] = p1;
        s_dst[(size_t)row * 8 + wv * 2]     = d0;
        s_dst[(size_t)row * 8 + wv * 2 + 1] = d1;
      }
    }
}

// ---- convert f32 score tables -> bf16 rows + fused per-head global max ----
__global__ __launch_bounds__(256) void k_cvt(const float* __restrict__ sf,
                                             unsigned short* __restrict__ sbf,
                                             unsigned int* __restrict__ mxbuf) {
  __shared__ unsigned int lmx[16];
  const int tid = threadIdx.x;
  if (tid < 16) lmx[tid] = 0u;
  __syncthreads();
  const int t = blockIdx.x * 256 + tid;
  if (t < 80000) {
    const f4* in = (const f4*)(sf + (size_t)t * 8);
    f4 v0 = in[0], v1 = in[1];
    u16x8 o;
    o[0] = f2bf(v0[0]); o[1] = f2bf(v0[1]); o[2] = f2bf(v0[2]); o[3] = f2bf(v0[3]);
    o[4] = f2bf(v1[0]); o[5] = f2bf(v1[1]); o[6] = f2bf(v1[2]); o[7] = f2bf(v1[3]);
    *(u16x8*)(sbf + (size_t)t * 8) = o;
    const int base = (t >= 40000) ? 8 : 0;
#pragma unroll
    for (int j = 0; j < 4; ++j) {
      atomicMax(&lmx[base + j],     ordf(v0[j]));
      atomicMax(&lmx[base + 4 + j], ordf(v1[j]));
    }
  }
  __syncthreads();
  if (tid < 16 && lmx[tid]) atomicMax(&mxbuf[tid], lmx[tid]);
}

// ---- LDS-privatized denom binning: block = (batch, head-pair, edge-slice) ----
// u32 fixed-point hist, native ds_add_u32 (fire & forget). U=4 batched loads for MLP.
__global__ __launch_bounds__(1024) void k_bin(const int* __restrict__ edge,
                                              const unsigned short* __restrict__ ssbf,
                                              const unsigned short* __restrict__ sdbf,
                                              const unsigned int* __restrict__ mxbuf,
                                              unsigned int* __restrict__ partial) {
  extern __shared__ unsigned int hist[];   // [2][NN]
  const int blk = blockIdx.x;              // ((b*4+hp)*NSLICE + r)
  const int r = blk & (NSLICE - 1);
  const int bh = blk / NSLICE;
  const int hp = bh & 3;
  const int b = bh >> 2;
  const int tid = threadIdx.x;
  for (int i = tid; i < 2 * NN; i += 1024) hist[i] = 0u;
  __syncthreads();
  const float MM0 = fmaxf(unordf(mxbuf[2 * hp])     + unordf(mxbuf[8 + 2 * hp]),     0.f);
  const float MM1 = fmaxf(unordf(mxbuf[2 * hp + 1]) + unordf(mxbuf[8 + 2 * hp + 1]), 0.f);
  const int* eps = edge + (size_t)b * 2 * EE + r * ESL;
  const int* epd = eps + EE;
  const unsigned short* ssb = ssbf + (size_t)b * NN * 8 + 2 * hp;
  const unsigned short* sdb = sdbf + (size_t)b * NN * 8 + 2 * hp;
  for (int base = 0; base < ESL; base += UU * 1024) {
    int src4[UU], dst4[UU];
    bool v4[UU];
    // phase 1: independent coalesced edge loads
#pragma unroll
    for (int u = 0; u < UU; ++u) {
      int i = base + tid + u * 1024;
      v4[u] = i < ESL;
      src4[u] = v4[u] ? eps[i] : 0;
      dst4[u] = v4[u] ? epd[i] : 0;
    }
    // phase 2: independent scattered 4-B gathers (8 in flight)
    unsigned su4[UU], du4[UU];
#pragma unroll
    for (int u = 0; u < UU; ++u) {
      su4[u] = *(const unsigned*)(ssb + (size_t)src4[u] * 8);
      du4[u] = *(const unsigned*)(sdb + (size_t)dst4[u] * 8);
    }
    // phase 3: compute + LDS atomics
#pragma unroll
    for (int u = 0; u < UU; ++u) {
      if (v4[u]) {
        float t0 = __uint_as_float(su4[u] << 16) + __uint_as_float(du4[u] << 16);
        float t1 = __uint_as_float(su4[u] & 0xFFFF0000u) + __uint_as_float(du4[u] & 0xFFFF0000u);
        t0 = t0 >= 0.f ? t0 : 0.2f * t0;
        t1 = t1 >= 0.f ? t1 : 0.2f * t1;
        atomicAdd(&hist[src4[u]], (unsigned)(__expf(t0 - MM0) * SCALE + 0.5f));
        atomicAdd(&hist[NN + src4[u]], (unsigned)(__expf(t1 - MM1) * SCALE + 0.5f));
      }
    }
  }
  __syncthreads();
  f4* pout = (f4*)(partial + (size_t)blk * (2 * NN));
  const f4* lin = (const f4*)hist;
  for (int i = tid; i < 2 * NN / 4; i += 1024) pout[i] = lin[i];
}

// ---- reduce NSLICE slice-partials (u32) -> denom (bf16 rows), exact int sums ----
__global__ __launch_bounds__(256) void k_reduce(const unsigned int* __restrict__ partial,
                                                unsigned short* __restrict__ dnbf) {
  const int t = blockIdx.x * 256 + threadIdx.x;       // (b*4+hp)*NN + seg
  if (t >= BB * 4 * NN) return;
  const int s = t % NN;
  const int c = t / NN;                               // c = b*4+hp
  const unsigned int* pp = partial + (size_t)c * NSLICE * 2 * NN;
  unsigned long long s0 = 0, s1 = 0;
#pragma unroll 8
  for (int r = 0; r < NSLICE; ++r) {
    s0 += pp[(size_t)r * 2 * NN + s];
    s1 += pp[(size_t)r * 2 * NN + NN + s];
  }
  const int b = c >> 2, hp = c & 3;
  unsigned pack = (unsigned)f2bf((float)s0 * INVSC) |
                  ((unsigned)f2bf((float)s1 * INVSC) << 16);
  *(unsigned*)(dnbf + ((size_t)b * NN + s) * 8 + 2 * hp) = pack;
}

// ---------------- finalize: att = exp(el - M) / denom ----------------
__global__ __launch_bounds__(256) void k_fin(const int* __restrict__ edge,
                                             const unsigned short* __restrict__ ssbf,
                                             const unsigned short* __restrict__ sdbf,
                                             const unsigned short* __restrict__ dnbf,
                                             const unsigned int* __restrict__ mxbuf,
                                             float* __restrict__ att) {
  const int idx = blockIdx.x * 256 + threadIdx.x;
  const int b = idx / EE;
  const int e = idx - b * EE;
  const int src = edge[(size_t)b * 2 * EE + e];
  const int dst = edge[(size_t)b * 2 * EE + EE + e];
  const size_t seg = (size_t)b * NN + src;
  float MM[8];
#pragma unroll
  for (int j = 0; j < 8; ++j)
    MM[j] = fmaxf(unordf(mxbuf[j]) + unordf(mxbuf[8 + j]), 0.f);
  u16x8 ss = *(const u16x8*)(ssbf + seg * 8);
  u16x8 sd = *(const u16x8*)(sdbf + ((size_t)b * NN + dst) * 8);
  u16x8 dn = *(const u16x8*)(dnbf + seg * 8);
  f4 o0, o1;
#pragma unroll
  for (int j = 0; j < 4; ++j) {
    float t0 = bf2f(ss[j]) + bf2f(sd[j]);
    t0 = t0 >= 0.f ? t0 : 0.2f * t0;
    float t1 = bf2f(ss[4 + j]) + bf2f(sd[4 + j]);
    t1 = t1 >= 0.f ? t1 : 0.2f * t1;
    float n0 = __expf(t0 - MM[j]);
    float n1 = __expf(t1 - MM[4 + j]);
    o0[j] = n0 / fmaxf(bf2f(dn[j]), n0);
    o1[j] = n1 / fmaxf(bf2f(dn[4 + j]), n1);
  }
  f4* op = (f4*)(att + (size_t)idx * 8);
  op[0] = o0;
  op[1] = o1;
}

extern "C" void kernel_launch(void* const* d_in, const int* in_sizes, int n_in,
                              void* d_out, int out_size, void* d_ws, size_t ws_size,
                              hipStream_t stream) {
  const float* x = (const float*)d_in[0];
  const int* edge = (const int*)d_in[1];
  const float* W = (const float*)d_in[2];
  const float* a = (const float*)d_in[3];

  float* att = (float*)d_out;                       // (B,E,H) = 10,240,000 f32 = 40.96 MB
  float* wx = att + (size_t)BB * EE * HH;           // (B,N,256) = 10,240,000 f32

  // partial histograms live in the att output region (dead until k_fin):
  // 512 blocks * 80000 B = 40.96 MB == att size exactly.
  unsigned int* partial = (unsigned int*)att;

  char* ws = (char*)d_ws;
  unsigned short* Wt = (unsigned short*)ws;                 // 128 KiB
  float* s_src = (float*)(ws + 131072);                     // 320000 f32
  float* s_dst = s_src + 320000;                            // 320000 f32 (contiguous after s_src)
  unsigned short* ssbf = (unsigned short*)(s_dst + 320000); // 320000 u16
  unsigned short* sdbf = ssbf + 320000;                     // 320000 u16 (contiguous)
  unsigned short* dnbf = sdbf + 320000;                     // 320000 u16
  unsigned int* mxbuf = (unsigned int*)(dnbf + 320000);     // 16 u32

  hipMemsetAsync(mxbuf, 0, 16 * sizeof(unsigned int), stream);
  hipFuncSetAttribute((const void*)k_bin, hipFuncAttributeMaxDynamicSharedMemorySize,
                      2 * NN * 4);

  k_transpose<<<dim3(4, 4), 256, 0, stream>>>(W, Wt);
  k_gemm<<<625, 256, 0, stream>>>(x, Wt, a, wx, s_src, s_dst);
  k_cvt<<<313, 256, 0, stream>>>(s_src, ssbf, mxbuf);       // converts s_src+s_dst + per-head max
  k_bin<<<BB * 4 * NSLICE, 1024, 2 * NN * 4, stream>>>(edge, ssbf, sdbf, mxbuf, partial);
  k_reduce<<<(BB * 4 * NN + 255) / 256, 256, 0, stream>>>(partial, dnbf);
  k_fin<<<5000, 256, 0, stream>>>(edge, ssbf, sdbf, dnbf, mxbuf, att);
}

// Round 11
// 96.386 us; speedup vs baseline: 1.3116x; 1.3116x over previous
//
#include <hip/hip_runtime.h>
#include <hip/hip_bf16.h>

#define BB 4
#define NN 10000
#define EE 320000
#define HH 8
#define NHQ 2                 // head halves
#define NRQ 2                 // src ranges per batch
#define SEGR (NN / NRQ)       // 5000 segments per range
#define NSLICE 16             // edge slices -> grid = 4*2*2*16 = 256 = 1 block/CU
#define ESL (EE / NSLICE)     // 20000 edges per slice
#define UU 4                  // edges batched per thread (MLP)
#define SCALE 16777216.0f     // 2^24 fixed-point
#define INVSC (1.0f / 16777216.0f)

typedef float f4 __attribute__((ext_vector_type(4)));
typedef short s8v __attribute__((ext_vector_type(8)));
typedef unsigned short u16x8 __attribute__((ext_vector_type(8)));

__device__ __forceinline__ unsigned short f2bf(float f) {
  unsigned int u = __float_as_uint(f);
  u += 0x7FFFu + ((u >> 16) & 1u);
  return (unsigned short)(u >> 16);
}
__device__ __forceinline__ float bf2f(unsigned short s) {
  return __uint_as_float(((unsigned int)s) << 16);
}
__device__ __forceinline__ unsigned int ordf(float f) {
  unsigned int u = __float_as_uint(f);
  return (u & 0x80000000u) ? ~u : (u | 0x80000000u);
}
__device__ __forceinline__ float unordf(unsigned int u) {
  unsigned int b = (u & 0x80000000u) ? (u & 0x7FFFFFFFu) : ~u;
  return __uint_as_float(b);
}

// ---------------- W transpose + bf16 convert: Wt[n][k] = bf16(W[k][n]) ----------------
__global__ __launch_bounds__(256) void k_transpose(const float* __restrict__ W,
                                                   unsigned short* __restrict__ Wt) {
  __shared__ float tile[64][65];
  const int n0 = blockIdx.x * 64, k0 = blockIdx.y * 64;
  for (int i = threadIdx.x; i < 4096; i += 256) {
    int kk = i >> 6, nn = i & 63;
    tile[kk][nn] = W[(size_t)(k0 + kk) * 256 + n0 + nn];
  }
  __syncthreads();
  for (int i = threadIdx.x; i < 4096; i += 256) {
    int nn = i >> 6, kk = i & 63;
    Wt[(size_t)(n0 + nn) * 256 + (k0 + kk)] = f2bf(tile[kk][nn]);
  }
}

// ---- GEMM + fused score epilogue: wx = x@W (bf16 MFMA), s_src/s_dst per row/head ----
__global__ __launch_bounds__(256, 2) void k_gemm(const float* __restrict__ x,
                                                 const unsigned short* __restrict__ Wt,
                                                 const float* __restrict__ a,
                                                 float* __restrict__ wx,
                                                 float* __restrict__ s_src,
                                                 float* __restrict__ s_dst) {
  __shared__ unsigned short sA[64][40];   // [row][k], padded
  __shared__ unsigned short sB[256][40];  // [col][k] (= W^T), padded
  const int tid = threadIdx.x;
  const int lane = tid & 63;
  const int wv = tid >> 6;
  const int row0 = blockIdx.x << 6;
  const int fr = lane & 15;
  const int fg = lane >> 4;
  f4 acc[4][4] = {};
  const int ar = tid >> 2;
  const int ak = (tid & 3) << 3;

  for (int k0 = 0; k0 < 256; k0 += 32) {
    const float* xp = x + (size_t)(row0 + ar) * 256 + k0 + ak;
    f4 v0 = *(const f4*)xp;
    f4 v1 = *(const f4*)(xp + 4);
    u16x8 av;
    av[0] = f2bf(v0[0]); av[1] = f2bf(v0[1]); av[2] = f2bf(v0[2]); av[3] = f2bf(v0[3]);
    av[4] = f2bf(v1[0]); av[5] = f2bf(v1[1]); av[6] = f2bf(v1[2]); av[7] = f2bf(v1[3]);
    *(u16x8*)&sA[ar][ak] = av;
#pragma unroll
    for (int j = 0; j < 4; ++j) {
      int ci = tid + (j << 8);
      int col = ci >> 2;
      int ks = (ci & 3) << 3;
      *(u16x8*)&sB[col][ks] = *(const u16x8*)(Wt + (size_t)col * 256 + k0 + ks);
    }
    __syncthreads();
    s8v afr[4], bfr[4];
#pragma unroll
    for (int m = 0; m < 4; ++m) afr[m] = *(const s8v*)&sA[m * 16 + fr][fg << 3];
#pragma unroll
    for (int n = 0; n < 4; ++n) bfr[n] = *(const s8v*)&sB[wv * 64 + n * 16 + fr][fg << 3];
#pragma unroll
    for (int m = 0; m < 4; ++m)
#pragma unroll
      for (int n = 0; n < 4; ++n)
        acc[m][n] = __builtin_amdgcn_mfma_f32_16x16x32_bf16(afr[m], bfr[n], acc[m][n], 0, 0, 0);
    __syncthreads();
  }
  // C store: D[row][col], col = lane&15, row = (lane>>4)*4 + q
#pragma unroll
  for (int m = 0; m < 4; ++m)
#pragma unroll
    for (int n = 0; n < 4; ++n) {
      int col = wv * 64 + n * 16 + fr;
#pragma unroll
      for (int q = 0; q < 4; ++q) {
        int row = row0 + m * 16 + fg * 4 + q;
        wx[(size_t)row * 256 + col] = acc[m][n][q];
      }
    }
  // fused scores: wave wv owns heads {2wv, 2wv+1}
  const float as0 = a[fr], as1 = a[16 + fr];
  const float ad0 = a[32 + fr], ad1 = a[48 + fr];
#pragma unroll
  for (int m = 0; m < 4; ++m)
#pragma unroll
    for (int q = 0; q < 4; ++q) {
      float p0 = acc[m][0][q] * as0 + acc[m][1][q] * as1;
      float p1 = acc[m][2][q] * as0 + acc[m][3][q] * as1;
      float d0 = acc[m][0][q] * ad0 + acc[m][1][q] * ad1;
      float d1 = acc[m][2][q] * ad0 + acc[m][3][q] * ad1;
#pragma unroll
      for (int msk = 1; msk <= 8; msk <<= 1) {
        p0 += __shfl_xor(p0, msk);
        p1 += __shfl_xor(p1, msk);
        d0 += __shfl_xor(d0, msk);
        d1 += __shfl_xor(d1, msk);
      }
      if (fr == 0) {
        int row = row0 + m * 16 + fg * 4 + q;
        s_src[(size_t)row * 8 + wv * 2]     = p0;
        s_src[(size_t)row * 8 + wv * 2 + 1] = p1;
        s_dst[(size_t)row * 8 + wv * 2]     = d0;
        s_dst[(size_t)row * 8 + wv * 2 + 1] = d1;
      }
    }
}

// ---- convert f32 score tables -> bf16 rows + fused per-head global max ----
__global__ __launch_bounds__(256) void k_cvt(const float* __restrict__ sf,
                                             unsigned short* __restrict__ sbf,
                                             unsigned int* __restrict__ mxbuf) {
  __shared__ unsigned int lmx[16];
  const int tid = threadIdx.x;
  if (tid < 16) lmx[tid] = 0u;
  __syncthreads();
  const int t = blockIdx.x * 256 + tid;
  if (t < 80000) {
    const f4* in = (const f4*)(sf + (size_t)t * 8);
    f4 v0 = in[0], v1 = in[1];
    u16x8 o;
    o[0] = f2bf(v0[0]); o[1] = f2bf(v0[1]); o[2] = f2bf(v0[2]); o[3] = f2bf(v0[3]);
    o[4] = f2bf(v1[0]); o[5] = f2bf(v1[1]); o[6] = f2bf(v1[2]); o[7] = f2bf(v1[3]);
    *(u16x8*)(sbf + (size_t)t * 8) = o;
    const int base = (t >= 40000) ? 8 : 0;
#pragma unroll
    for (int j = 0; j < 4; ++j) {
      atomicMax(&lmx[base + j],     ordf(v0[j]));
      atomicMax(&lmx[base + 4 + j], ordf(v1[j]));
    }
  }
  __syncthreads();
  if (tid < 16 && lmx[tid]) atomicMax(&mxbuf[tid], lmx[tid]);
}

// ---- LDS-privatized denom binning: block = (batch, head-half, src-range, slice) ----
// Per edge: ONE scattered 8-B dst gather (src half-row from 40 KB LDS stage).
// hist = u32 fixed-point, native ds_add_u32. LDS = 80K hist + 40K stage = 120 KB.
__global__ __launch_bounds__(1024) void k_bin(const int* __restrict__ edge,
                                              const unsigned short* __restrict__ ssbf,
                                              const unsigned short* __restrict__ sdbf,
                                              const unsigned int* __restrict__ mxbuf,
                                              unsigned int* __restrict__ partial) {
  extern __shared__ unsigned int ldsu[];
  unsigned int* hist = ldsu;                      // [4][SEGR] u32
  uint2* stg = (uint2*)(ldsu + 4 * SEGR);         // [SEGR] 8-B src half-rows
  const int blk = blockIdx.x;                     // ((b*2+hq)*2+rq)*NSLICE + r
  const int r = blk & (NSLICE - 1);
  const int c = blk / NSLICE;
  const int rq = c & 1;
  const int hq = (c >> 1) & 1;
  const int b = c >> 2;
  const int tid = threadIdx.x;
  const int lo = rq * SEGR;
  for (int i = tid; i < 4 * SEGR; i += 1024) hist[i] = 0u;
  // stage src half-rows [lo, lo+SEGR): 8 B each (4 heads bf16)
  const unsigned short* ssb = ssbf + ((size_t)b * NN + lo) * 8 + hq * 4;
  for (int i = tid; i < SEGR; i += 1024) stg[i] = *(const uint2*)(ssb + (size_t)i * 8);
  __syncthreads();
  float MH[4];
#pragma unroll
  for (int j = 0; j < 4; ++j)
    MH[j] = fmaxf(unordf(mxbuf[hq * 4 + j]) + unordf(mxbuf[8 + hq * 4 + j]), 0.f);
  const int* eps = edge + (size_t)b * 2 * EE + r * ESL;
  const int* epd = eps + EE;
  const unsigned short* sdb = sdbf + (size_t)b * NN * 8 + hq * 4;
  for (int base = 0; base < ESL; base += UU * 1024) {
    int ls4[UU], dst4[UU];
    bool v4[UU];
#pragma unroll
    for (int u = 0; u < UU; ++u) {
      int i = base + tid + u * 1024;
      bool inb = i < ESL;
      int s = inb ? eps[i] : 0;
      dst4[u] = inb ? epd[i] : 0;
      int ls = s - lo;
      v4[u] = inb && ((unsigned)ls < (unsigned)SEGR);
      ls4[u] = ls;
    }
    uint2 du4[UU];
#pragma unroll
    for (int u = 0; u < UU; ++u)
      if (v4[u]) du4[u] = *(const uint2*)(sdb + (size_t)dst4[u] * 8);
#pragma unroll
    for (int u = 0; u < UU; ++u) {
      if (v4[u]) {
        uint2 su = stg[ls4[u]];
        float t0 = __uint_as_float(su.x << 16) + __uint_as_float(du4[u].x << 16);
        float t1 = __uint_as_float(su.x & 0xFFFF0000u) + __uint_as_float(du4[u].x & 0xFFFF0000u);
        float t2 = __uint_as_float(su.y << 16) + __uint_as_float(du4[u].y << 16);
        float t3 = __uint_as_float(su.y & 0xFFFF0000u) + __uint_as_float(du4[u].y & 0xFFFF0000u);
        t0 = t0 >= 0.f ? t0 : 0.2f * t0;
        t1 = t1 >= 0.f ? t1 : 0.2f * t1;
        t2 = t2 >= 0.f ? t2 : 0.2f * t2;
        t3 = t3 >= 0.f ? t3 : 0.2f * t3;
        atomicAdd(&hist[0 * SEGR + ls4[u]], (unsigned)(__expf(t0 - MH[0]) * SCALE + 0.5f));
        atomicAdd(&hist[1 * SEGR + ls4[u]], (unsigned)(__expf(t1 - MH[1]) * SCALE + 0.5f));
        atomicAdd(&hist[2 * SEGR + ls4[u]], (unsigned)(__expf(t2 - MH[2]) * SCALE + 0.5f));
        atomicAdd(&hist[3 * SEGR + ls4[u]], (unsigned)(__expf(t3 - MH[3]) * SCALE + 0.5f));
      }
    }
  }
  __syncthreads();
  f4* pout = (f4*)(partial + (size_t)blk * (4 * SEGR));
  const f4* lin = (const f4*)hist;
  for (int i = tid; i < SEGR; i += 1024) pout[i] = lin[i];
}

// ---- reduce NSLICE slice-partials (u32) -> denom (bf16 half-rows), exact int sums ----
__global__ __launch_bounds__(256) void k_reduce(const unsigned int* __restrict__ partial,
                                                unsigned short* __restrict__ dnbf) {
  const int t = blockIdx.x * 256 + threadIdx.x;   // BB*NHQ*NRQ*SEGR = 80000
  if (t >= BB * NHQ * NRQ * SEGR) return;
  const int ls = t % SEGR;
  const int c = t / SEGR;                         // ((b*2+hq)*2+rq)
  const unsigned int* pp = partial + (size_t)c * NSLICE * (4 * SEGR);
  unsigned long long s[4] = {0, 0, 0, 0};
#pragma unroll 4
  for (int r = 0; r < NSLICE; ++r)
#pragma unroll
    for (int h = 0; h < 4; ++h)
      s[h] += pp[(size_t)r * (4 * SEGR) + h * SEGR + ls];
  const int rq = c & 1, hq = (c >> 1) & 1, b = c >> 2;
  uint2 pk;
  pk.x = (unsigned)f2bf((float)s[0] * INVSC) | ((unsigned)f2bf((float)s[1] * INVSC) << 16);
  pk.y = (unsigned)f2bf((float)s[2] * INVSC) | ((unsigned)f2bf((float)s[3] * INVSC) << 16);
  *(uint2*)(dnbf + ((size_t)b * NN + rq * SEGR + ls) * 8 + hq * 4) = pk;
}

// ---------------- finalize: att = exp(el - M) / denom ----------------
__global__ __launch_bounds__(256) void k_fin(const int* __restrict__ edge,
                                             const unsigned short* __restrict__ ssbf,
                                             const unsigned short* __restrict__ sdbf,
                                             const unsigned short* __restrict__ dnbf,
                                             const unsigned int* __restrict__ mxbuf,
                                             float* __restrict__ att) {
  const int idx = blockIdx.x * 256 + threadIdx.x;
  const int b = idx / EE;
  const int e = idx - b * EE;
  const int src = edge[(size_t)b * 2 * EE + e];
  const int dst = edge[(size_t)b * 2 * EE + EE + e];
  const size_t seg = (size_t)b * NN + src;
  float MM[8];
#pragma unroll
  for (int j = 0; j < 8; ++j)
    MM[j] = fmaxf(unordf(mxbuf[j]) + unordf(mxbuf[8 + j]), 0.f);
  u16x8 ss = *(const u16x8*)(ssbf + seg * 8);
  u16x8 sd = *(const u16x8*)(sdbf + ((size_t)b * NN + dst) * 8);
  u16x8 dn = *(const u16x8*)(dnbf + seg * 8);
  f4 o0, o1;
#pragma unroll
  for (int j = 0; j < 4; ++j) {
    float t0 = bf2f(ss[j]) + bf2f(sd[j]);
    t0 = t0 >= 0.f ? t0 : 0.2f * t0;
    float t1 = bf2f(ss[4 + j]) + bf2f(sd[4 + j]);
    t1 = t1 >= 0.f ? t1 : 0.2f * t1;
    float n0 = __expf(t0 - MM[j]);
    float n1 = __expf(t1 - MM[4 + j]);
    o0[j] = n0 / fmaxf(bf2f(dn[j]), n0);
    o1[j] = n1 / fmaxf(bf2f(dn[4 + j]), n1);
  }
  f4* op = (f4*)(att + (size_t)idx * 8);
  op[0] = o0;
  op[1] = o1;
}

extern "C" void kernel_launch(void* const* d_in, const int* in_sizes, int n_in,
                              void* d_out, int out_size, void* d_ws, size_t ws_size,
                              hipStream_t stream) {
  const float* x = (const float*)d_in[0];
  const int* edge = (const int*)d_in[1];
  const float* W = (const float*)d_in[2];
  const float* a = (const float*)d_in[3];

  float* att = (float*)d_out;                       // (B,E,H) = 10,240,000 f32 = 40.96 MB
  float* wx = att + (size_t)BB * EE * HH;           // (B,N,256) = 10,240,000 f32

  // partial histograms live in the att output region (dead until k_fin):
  // 256 blocks * 80000 B = 20.48 MB < 40.96 MB.
  unsigned int* partial = (unsigned int*)att;

  char* ws = (char*)d_ws;
  unsigned short* Wt = (unsigned short*)ws;                 // 128 KiB
  float* s_src = (float*)(ws + 131072);                     // 320000 f32
  float* s_dst = s_src + 320000;                            // 320000 f32 (contiguous after s_src)
  unsigned short* ssbf = (unsigned short*)(s_dst + 320000); // 320000 u16
  unsigned short* sdbf = ssbf + 320000;                     // 320000 u16 (contiguous)
  unsigned short* dnbf = sdbf + 320000;                     // 320000 u16
  unsigned int* mxbuf = (unsigned int*)(dnbf + 320000);     // 16 u32

  hipMemsetAsync(mxbuf, 0, 16 * sizeof(unsigned int), stream);
  hipFuncSetAttribute((const void*)k_bin, hipFuncAttributeMaxDynamicSharedMemorySize,
                      4 * SEGR * 4 + SEGR * 8);

  k_transpose<<<dim3(4, 4), 256, 0, stream>>>(W, Wt);
  k_gemm<<<625, 256, 0, stream>>>(x, Wt, a, wx, s_src, s_dst);
  k_cvt<<<313, 256, 0, stream>>>(s_src, ssbf, mxbuf);       // converts s_src+s_dst + per-head max
  k_bin<<<BB * NHQ * NRQ * NSLICE, 1024, 4 * SEGR * 4 + SEGR * 8, stream>>>(edge, ssbf, sdbf, mxbuf, partial);
  k_reduce<<<(BB * NHQ * NRQ * SEGR + 255) / 256, 256, 0, stream>>>(partial, dnbf);
  k_fin<<<5000, 256, 0, stream>>>(edge, ssbf, sdbf, dnbf, mxbuf, att);
}

// Round 12
// 89.778 us; speedup vs baseline: 1.4081x; 1.0736x over previous
//
#include <hip/hip_runtime.h>
#include <hip/hip_bf16.h>

#define BB 4
#define NN 10000
#define EE 320000
#define HH 8
#define NHQ 2                 // head halves
#define NRQ 2                 // src ranges per batch
#define SEGR (NN / NRQ)       // 5000 segments per range
#define NSLICE 16             // edge slices -> grid = 4*2*2*16 = 256 = 1 block/CU
#define ESL (EE / NSLICE)     // 20000 edges per slice
#define UU 4                  // edges batched per thread (MLP)
#define SCALE 16777216.0f     // 2^24 fixed-point
#define INVSC (1.0f / 16777216.0f)

typedef float f4 __attribute__((ext_vector_type(4)));
typedef short s8v __attribute__((ext_vector_type(8)));
typedef unsigned short u16x8 __attribute__((ext_vector_type(8)));

__device__ __forceinline__ unsigned short f2bf(float f) {
  unsigned int u = __float_as_uint(f);
  u += 0x7FFFu + ((u >> 16) & 1u);
  return (unsigned short)(u >> 16);
}
__device__ __forceinline__ float bf2f(unsigned short s) {
  return __uint_as_float(((unsigned int)s) << 16);
}
__device__ __forceinline__ unsigned int ordf(float f) {
  unsigned int u = __float_as_uint(f);
  return (u & 0x80000000u) ? ~u : (u | 0x80000000u);
}
__device__ __forceinline__ float unordf(unsigned int u) {
  unsigned int b = (u & 0x80000000u) ? (u & 0x7FFFFFFFu) : ~u;
  return __uint_as_float(b);
}

// ------- W transpose + bf16 convert: Wt[n][k] = bf16(W[k][n]); also zeroes mxbuf -------
__global__ __launch_bounds__(256) void k_transpose(const float* __restrict__ W,
                                                   unsigned short* __restrict__ Wt,
                                                   unsigned int* __restrict__ mxbuf) {
  if (blockIdx.x == 0 && blockIdx.y == 0 && threadIdx.x < 16) mxbuf[threadIdx.x] = 0u;
  __shared__ float tile[64][65];
  const int n0 = blockIdx.x * 64, k0 = blockIdx.y * 64;
  for (int i = threadIdx.x; i < 4096; i += 256) {
    int kk = i >> 6, nn = i & 63;
    tile[kk][nn] = W[(size_t)(k0 + kk) * 256 + n0 + nn];
  }
  __syncthreads();
  for (int i = threadIdx.x; i < 4096; i += 256) {
    int nn = i >> 6, kk = i & 63;
    Wt[(size_t)(n0 + nn) * 256 + (k0 + kk)] = f2bf(tile[kk][nn]);
  }
}

// ---- GEMM + fused score epilogue: wx = x@W (bf16 MFMA); writes bf16 score rows
// ---- ssbf/sdbf directly + per-head global max (LDS -> global atomicMax). ----
__global__ __launch_bounds__(256, 2) void k_gemm(const float* __restrict__ x,
                                                 const unsigned short* __restrict__ Wt,
                                                 const float* __restrict__ a,
                                                 float* __restrict__ wx,
                                                 unsigned short* __restrict__ ssbf,
                                                 unsigned short* __restrict__ sdbf,
                                                 unsigned int* __restrict__ mxbuf) {
  __shared__ unsigned short sA[64][40];   // [row][k], padded
  __shared__ unsigned short sB[256][40];  // [col][k] (= W^T), padded
  __shared__ unsigned int lmx[16];
  const int tid = threadIdx.x;
  const int lane = tid & 63;
  const int wv = tid >> 6;
  const int row0 = blockIdx.x << 6;
  const int fr = lane & 15;
  const int fg = lane >> 4;
  f4 acc[4][4] = {};
  const int ar = tid >> 2;
  const int ak = (tid & 3) << 3;
  if (tid < 16) lmx[tid] = 0u;

  for (int k0 = 0; k0 < 256; k0 += 32) {
    const float* xp = x + (size_t)(row0 + ar) * 256 + k0 + ak;
    f4 v0 = *(const f4*)xp;
    f4 v1 = *(const f4*)(xp + 4);
    u16x8 av;
    av[0] = f2bf(v0[0]); av[1] = f2bf(v0[1]); av[2] = f2bf(v0[2]); av[3] = f2bf(v0[3]);
    av[4] = f2bf(v1[0]); av[5] = f2bf(v1[1]); av[6] = f2bf(v1[2]); av[7] = f2bf(v1[3]);
    *(u16x8*)&sA[ar][ak] = av;
#pragma unroll
    for (int j = 0; j < 4; ++j) {
      int ci = tid + (j << 8);
      int col = ci >> 2;
      int ks = (ci & 3) << 3;
      *(u16x8*)&sB[col][ks] = *(const u16x8*)(Wt + (size_t)col * 256 + k0 + ks);
    }
    __syncthreads();
    s8v afr[4], bfr[4];
#pragma unroll
    for (int m = 0; m < 4; ++m) afr[m] = *(const s8v*)&sA[m * 16 + fr][fg << 3];
#pragma unroll
    for (int n = 0; n < 4; ++n) bfr[n] = *(const s8v*)&sB[wv * 64 + n * 16 + fr][fg << 3];
#pragma unroll
    for (int m = 0; m < 4; ++m)
#pragma unroll
      for (int n = 0; n < 4; ++n)
        acc[m][n] = __builtin_amdgcn_mfma_f32_16x16x32_bf16(afr[m], bfr[n], acc[m][n], 0, 0, 0);
    __syncthreads();
  }
  // C store: D[row][col], col = lane&15, row = (lane>>4)*4 + q
#pragma unroll
  for (int m = 0; m < 4; ++m)
#pragma unroll
    for (int n = 0; n < 4; ++n) {
      int col = wv * 64 + n * 16 + fr;
#pragma unroll
      for (int q = 0; q < 4; ++q) {
        int row = row0 + m * 16 + fg * 4 + q;
        wx[(size_t)row * 256 + col] = acc[m][n][q];
      }
    }
  // fused scores: wave wv owns heads {2wv, 2wv+1}; butterfly leaves sums in ALL lanes
  const float as0 = a[fr], as1 = a[16 + fr];
  const float ad0 = a[32 + fr], ad1 = a[48 + fr];
  unsigned mp0 = 0u, mp1 = 0u, md0 = 0u, md1 = 0u;   // ordf running maxes
#pragma unroll
  for (int m = 0; m < 4; ++m)
#pragma unroll
    for (int q = 0; q < 4; ++q) {
      float p0 = acc[m][0][q] * as0 + acc[m][1][q] * as1;
      float p1 = acc[m][2][q] * as0 + acc[m][3][q] * as1;
      float d0 = acc[m][0][q] * ad0 + acc[m][1][q] * ad1;
      float d1 = acc[m][2][q] * ad0 + acc[m][3][q] * ad1;
#pragma unroll
      for (int msk = 1; msk <= 8; msk <<= 1) {
        p0 += __shfl_xor(p0, msk);
        p1 += __shfl_xor(p1, msk);
        d0 += __shfl_xor(d0, msk);
        d1 += __shfl_xor(d1, msk);
      }
      mp0 = max(mp0, ordf(p0)); mp1 = max(mp1, ordf(p1));
      md0 = max(md0, ordf(d0)); md1 = max(md1, ordf(d1));
      if (fr == 0) {
        int row = row0 + m * 16 + fg * 4 + q;
        unsigned sspk = (unsigned)f2bf(p0) | ((unsigned)f2bf(p1) << 16);
        unsigned sdpk = (unsigned)f2bf(d0) | ((unsigned)f2bf(d1) << 16);
        ((unsigned*)ssbf)[(size_t)row * 4 + wv] = sspk;
        ((unsigned*)sdbf)[(size_t)row * 4 + wv] = sdpk;
      }
    }
  if (fr == 0) {
    atomicMax(&lmx[wv * 2],     mp0);
    atomicMax(&lmx[wv * 2 + 1], mp1);
    atomicMax(&lmx[8 + wv * 2],     md0);
    atomicMax(&lmx[8 + wv * 2 + 1], md1);
  }
  __syncthreads();
  if (tid < 16 && lmx[tid]) atomicMax(&mxbuf[tid], lmx[tid]);
}

// ---- LDS-privatized denom binning: block = (batch, head-half, src-range, slice) ----
// Per edge: ONE scattered 8-B dst gather (src half-row from 40 KB LDS stage).
// hist = u32 fixed-point, native ds_add_u32. LDS = 80K hist + 40K stage = 120 KB.
__global__ __launch_bounds__(1024) void k_bin(const int* __restrict__ edge,
                                              const unsigned short* __restrict__ ssbf,
                                              const unsigned short* __restrict__ sdbf,
                                              const unsigned int* __restrict__ mxbuf,
                                              unsigned int* __restrict__ partial) {
  extern __shared__ unsigned int ldsu[];
  unsigned int* hist = ldsu;                      // [4][SEGR] u32
  uint2* stg = (uint2*)(ldsu + 4 * SEGR);         // [SEGR] 8-B src half-rows
  const int blk = blockIdx.x;                     // ((b*2+hq)*2+rq)*NSLICE + r
  const int r = blk & (NSLICE - 1);
  const int c = blk / NSLICE;
  const int rq = c & 1;
  const int hq = (c >> 1) & 1;
  const int b = c >> 2;
  const int tid = threadIdx.x;
  const int lo = rq * SEGR;
  for (int i = tid; i < 4 * SEGR; i += 1024) hist[i] = 0u;
  const unsigned short* ssb = ssbf + ((size_t)b * NN + lo) * 8 + hq * 4;
  for (int i = tid; i < SEGR; i += 1024) stg[i] = *(const uint2*)(ssb + (size_t)i * 8);
  __syncthreads();
  float MH[4];
#pragma unroll
  for (int j = 0; j < 4; ++j)
    MH[j] = fmaxf(unordf(mxbuf[hq * 4 + j]) + unordf(mxbuf[8 + hq * 4 + j]), 0.f);
  const int* eps = edge + (size_t)b * 2 * EE + r * ESL;
  const int* epd = eps + EE;
  const unsigned short* sdb = sdbf + (size_t)b * NN * 8 + hq * 4;
  for (int base = 0; base < ESL; base += UU * 1024) {
    int ls4[UU], dst4[UU];
    bool v4[UU];
#pragma unroll
    for (int u = 0; u < UU; ++u) {
      int i = base + tid + u * 1024;
      bool inb = i < ESL;
      int s = inb ? eps[i] : 0;
      dst4[u] = inb ? epd[i] : 0;
      int ls = s - lo;
      v4[u] = inb && ((unsigned)ls < (unsigned)SEGR);
      ls4[u] = ls;
    }
    uint2 du4[UU];
#pragma unroll
    for (int u = 0; u < UU; ++u)
      if (v4[u]) du4[u] = *(const uint2*)(sdb + (size_t)dst4[u] * 8);
#pragma unroll
    for (int u = 0; u < UU; ++u) {
      if (v4[u]) {
        uint2 su = stg[ls4[u]];
        float t0 = __uint_as_float(su.x << 16) + __uint_as_float(du4[u].x << 16);
        float t1 = __uint_as_float(su.x & 0xFFFF0000u) + __uint_as_float(du4[u].x & 0xFFFF0000u);
        float t2 = __uint_as_float(su.y << 16) + __uint_as_float(du4[u].y << 16);
        float t3 = __uint_as_float(su.y & 0xFFFF0000u) + __uint_as_float(du4[u].y & 0xFFFF0000u);
        t0 = t0 >= 0.f ? t0 : 0.2f * t0;
        t1 = t1 >= 0.f ? t1 : 0.2f * t1;
        t2 = t2 >= 0.f ? t2 : 0.2f * t2;
        t3 = t3 >= 0.f ? t3 : 0.2f * t3;
        atomicAdd(&hist[0 * SEGR + ls4[u]], (unsigned)(__expf(t0 - MH[0]) * SCALE + 0.5f));
        atomicAdd(&hist[1 * SEGR + ls4[u]], (unsigned)(__expf(t1 - MH[1]) * SCALE + 0.5f));
        atomicAdd(&hist[2 * SEGR + ls4[u]], (unsigned)(__expf(t2 - MH[2]) * SCALE + 0.5f));
        atomicAdd(&hist[3 * SEGR + ls4[u]], (unsigned)(__expf(t3 - MH[3]) * SCALE + 0.5f));
      }
    }
  }
  __syncthreads();
  f4* pout = (f4*)(partial + (size_t)blk * (4 * SEGR));
  const f4* lin = (const f4*)hist;
  for (int i = tid; i < SEGR; i += 1024) pout[i] = lin[i];
}

// ---- reduce NSLICE slice-partials (u32) -> denom (bf16 half-rows), exact int sums ----
__global__ __launch_bounds__(256) void k_reduce(const unsigned int* __restrict__ partial,
                                                unsigned short* __restrict__ dnbf) {
  const int t = blockIdx.x * 256 + threadIdx.x;   // BB*NHQ*NRQ*SEGR = 80000
  if (t >= BB * NHQ * NRQ * SEGR) return;
  const int ls = t % SEGR;
  const int c = t / SEGR;                         // ((b*2+hq)*2+rq)
  const unsigned int* pp = partial + (size_t)c * NSLICE * (4 * SEGR);
  unsigned long long s[4] = {0, 0, 0, 0};
#pragma unroll 4
  for (int r = 0; r < NSLICE; ++r)
#pragma unroll
    for (int h = 0; h < 4; ++h)
      s[h] += pp[(size_t)r * (4 * SEGR) + h * SEGR + ls];
  const int rq = c & 1, hq = (c >> 1) & 1, b = c >> 2;
  uint2 pk;
  pk.x = (unsigned)f2bf((float)s[0] * INVSC) | ((unsigned)f2bf((float)s[1] * INVSC) << 16);
  pk.y = (unsigned)f2bf((float)s[2] * INVSC) | ((unsigned)f2bf((float)s[3] * INVSC) << 16);
  *(uint2*)(dnbf + ((size_t)b * NN + rq * SEGR + ls) * 8 + hq * 4) = pk;
}

// ---------------- finalize: att = exp(el - M) / denom ----------------
__global__ __launch_bounds__(256) void k_fin(const int* __restrict__ edge,
                                             const unsigned short* __restrict__ ssbf,
                                             const unsigned short* __restrict__ sdbf,
                                             const unsigned short* __restrict__ dnbf,
                                             const unsigned int* __restrict__ mxbuf,
                                             float* __restrict__ att) {
  const int idx = blockIdx.x * 256 + threadIdx.x;
  const int b = idx / EE;
  const int e = idx - b * EE;
  const int src = edge[(size_t)b * 2 * EE + e];
  const int dst = edge[(size_t)b * 2 * EE + EE + e];
  const size_t seg = (size_t)b * NN + src;
  float MM[8];
#pragma unroll
  for (int j = 0; j < 8; ++j)
    MM[j] = fmaxf(unordf(mxbuf[j]) + unordf(mxbuf[8 + j]), 0.f);
  u16x8 ss = *(const u16x8*)(ssbf + seg * 8);
  u16x8 sd = *(const u16x8*)(sdbf + ((size_t)b * NN + dst) * 8);
  u16x8 dn = *(const u16x8*)(dnbf + seg * 8);
  f4 o0, o1;
#pragma unroll
  for (int j = 0; j < 4; ++j) {
    float t0 = bf2f(ss[j]) + bf2f(sd[j]);
    t0 = t0 >= 0.f ? t0 : 0.2f * t0;
    float t1 = bf2f(ss[4 + j]) + bf2f(sd[4 + j]);
    t1 = t1 >= 0.f ? t1 : 0.2f * t1;
    float n0 = __expf(t0 - MM[j]);
    float n1 = __expf(t1 - MM[4 + j]);
    o0[j] = n0 / fmaxf(bf2f(dn[j]), n0);
    o1[j] = n1 / fmaxf(bf2f(dn[4 + j]), n1);
  }
  f4* op = (f4*)(att + (size_t)idx * 8);
  op[0] = o0;
  op[1] = o1;
}

extern "C" void kernel_launch(void* const* d_in, const int* in_sizes, int n_in,
                              void* d_out, int out_size, void* d_ws, size_t ws_size,
                              hipStream_t stream) {
  const float* x = (const float*)d_in[0];
  const int* edge = (const int*)d_in[1];
  const float* W = (const float*)d_in[2];
  const float* a = (const float*)d_in[3];

  float* att = (float*)d_out;                       // (B,E,H) = 10,240,000 f32 = 40.96 MB
  float* wx = att + (size_t)BB * EE * HH;           // (B,N,256) = 10,240,000 f32

  // partial histograms live in the att output region (dead until k_fin):
  // 256 blocks * 80000 B = 20.48 MB < 40.96 MB.
  unsigned int* partial = (unsigned int*)att;

  char* ws = (char*)d_ws;
  unsigned short* Wt = (unsigned short*)ws;                 // 128 KiB
  unsigned short* ssbf = (unsigned short*)(ws + 131072);    // 320000 u16
  unsigned short* sdbf = ssbf + 320000;                     // 320000 u16
  unsigned short* dnbf = sdbf + 320000;                     // 320000 u16
  unsigned int* mxbuf = (unsigned int*)(dnbf + 320000);     // 16 u32

  hipFuncSetAttribute((const void*)k_bin, hipFuncAttributeMaxDynamicSharedMemorySize,
                      4 * SEGR * 4 + SEGR * 8);

  k_transpose<<<dim3(4, 4), 256, 0, stream>>>(W, Wt, mxbuf);
  k_gemm<<<625, 256, 0, stream>>>(x, Wt, a, wx, ssbf, sdbf, mxbuf);
  k_bin<<<BB * NHQ * NRQ * NSLICE, 1024, 4 * SEGR * 4 + SEGR * 8, stream>>>(edge, ssbf, sdbf, mxbuf, partial);
  k_reduce<<<(BB * NHQ * NRQ * SEGR + 255) / 256, 256, 0, stream>>>(partial, dnbf);
  k_fin<<<5000, 256, 0, stream>>>(edge, ssbf, sdbf, dnbf, mxbuf, att);
}